// Round 1
// baseline (9084.687 us; speedup 1.0000x reference)
//
#include <hip/hip_runtime.h>
#include <math.h>

// NonlinearFilter: B=128 independent chains, T=256 sequential steps each.
// One workgroup per batch element; weights + particle state live in LDS.
// Round 1: correctness-first fp32 VALU version.

namespace {
constexpr int B = 128;
constexpr int T = 256;
constexpr int L = 64;
constexpr int S = 25;
constexpr int H = 128;
constexpr int NT = 512;          // 8 waves

__device__ __forceinline__ float softplus_f(float x) {
    // matches jax.nn.softplus = logaddexp(x, 0)
    return fmaxf(x, 0.0f) + log1pf(expf(-fabsf(x)));
}
} // namespace

__global__ __launch_bounds__(NT, 1)
void nlf_kernel(const float* __restrict__ kk,
                const float* __restrict__ KK,
                const float* __restrict__ noise,
                const float* __restrict__ log_Q,
                const float* __restrict__ m_0,
                const float* __restrict__ log_Q_0,
                const float* __restrict__ W1,
                const float* __restrict__ b1,
                const float* __restrict__ W2,
                const float* __restrict__ b2,
                float* __restrict__ out)
{
    const int b   = blockIdx.x;
    const int tid = threadIdx.x;

    __shared__ __align__(16) float sW1[L][H];   // 32 KB
    __shared__ __align__(16) float sW2[H][L];   // 32 KB
    __shared__ __align__(16) float sTh[S][H];   // tanh activations, 12.8 KB
    __shared__ __align__(16) float sZ[S][L];    // z / m_th (in-place), 6.4 KB
    __shared__ __align__(16) float sB1[H];
    __shared__ __align__(16) float sB2[L];
    __shared__ float sQd[L];
    __shared__ float sMf[L];
    __shared__ float sSPf[L];

    // ---- stage weights / constants into LDS ----
    for (int i = tid; i < L * H; i += NT) sW1[0][i] = W1[i];
    for (int i = tid; i < H * L; i += NT) sW2[0][i] = W2[i];
    if (tid < H) sB1[tid] = b1[tid];
    if (tid < L) {
        sB2[tid] = b2[tid];
        sQd[tid] = softplus_f(log_Q[tid]);
    }

    float* out_zf = out;                                  // (S,B,T,L)
    float* out_mf = out + (size_t)S * B * T * L;          // (B,T,L)
    float* out_mp = out_mf + (size_t)B * T * L;
    float* out_Pf = out_mp + (size_t)B * T * L;
    float* out_Pp = out_Pf + (size_t)B * T * L;

    // ---- t = 0 ----
    if (tid < L) {
        const int l = tid;
        const float P0  = softplus_f(log_Q_0[l]);
        const float J0  = 1.0f / P0;
        const float h0  = J0 * m_0[l];
        const float Kv  = KK[((size_t)b * T + 0) * L + l];
        const float kv  = kk[((size_t)b * T + 0) * L + l];
        const float Jf  = J0 + Kv;
        const float Pf  = 1.0f / Jf;
        const float mf  = Pf * (h0 + kv);
        const size_t o  = ((size_t)b * T + 0) * L + l;
        out_mf[o] = mf;
        out_mp[o] = m_0[l];
        out_Pf[o] = Pf;
        out_Pp[o] = P0;
        sMf[l]  = mf;
        sSPf[l] = sqrtf(Pf);
    }
    __syncthreads();

    // z_0 = m_f0 + sqrt(P_f0) * noise[0]
    if (tid < S * (L / 4)) {
        const int s = tid >> 4;
        const int i = (tid & 15) * 4;
        const float4 nv = *(const float4*)&noise[(((size_t)0 * S + s) * B + b) * L + i];
        float4 z;
        z.x = sMf[i + 0] + sSPf[i + 0] * nv.x;
        z.y = sMf[i + 1] + sSPf[i + 1] * nv.y;
        z.z = sMf[i + 2] + sSPf[i + 2] * nv.z;
        z.w = sMf[i + 3] + sSPf[i + 3] * nv.w;
        *(float4*)&sZ[s][i] = z;
        *(float4*)&out_zf[(((size_t)s * B + b) * T + 0) * L + i] = z;
    }
    __syncthreads();

    // ---- main scan: t = 1 .. T-1 ----
    for (int t = 1; t < T; ++t) {
        // prefetch step inputs (consumed after the GEMMs; latency hidden)
        float kv = 0.0f, Kv = 0.0f;
        if (tid < L) {
            kv = kk[((size_t)b * T + t) * L + tid];
            Kv = KK[((size_t)b * T + t) * L + tid];
        }
        float4 nv = make_float4(0.f, 0.f, 0.f, 0.f);
        int zs = 0, zi = 0;
        if (tid < S * (L / 4)) {
            zs = tid >> 4;
            zi = (tid & 15) * 4;
            nv = *(const float4*)&noise[(((size_t)t * S + zs) * B + b) * L + zi];
        }

        // GEMM1 + tanh: sTh[s][j] = tanh(b1[j] + sum_l sZ[s][l] * W1[l][j])
        for (int idx = tid; idx < S * (H / 4); idx += NT) {
            const int s = idx >> 5;          // H/4 = 32 groups
            const int j = (idx & 31) * 4;
            float4 acc = *(const float4*)&sB1[j];
            #pragma unroll
            for (int l = 0; l < L; l += 4) {
                const float4 zq = *(const float4*)&sZ[s][l];
                const float4 w0 = *(const float4*)&sW1[l + 0][j];
                const float4 w1 = *(const float4*)&sW1[l + 1][j];
                const float4 w2 = *(const float4*)&sW1[l + 2][j];
                const float4 w3 = *(const float4*)&sW1[l + 3][j];
                acc.x = fmaf(zq.x, w0.x, acc.x); acc.y = fmaf(zq.x, w0.y, acc.y);
                acc.z = fmaf(zq.x, w0.z, acc.z); acc.w = fmaf(zq.x, w0.w, acc.w);
                acc.x = fmaf(zq.y, w1.x, acc.x); acc.y = fmaf(zq.y, w1.y, acc.y);
                acc.z = fmaf(zq.y, w1.z, acc.z); acc.w = fmaf(zq.y, w1.w, acc.w);
                acc.x = fmaf(zq.z, w2.x, acc.x); acc.y = fmaf(zq.z, w2.y, acc.y);
                acc.z = fmaf(zq.z, w2.z, acc.z); acc.w = fmaf(zq.z, w2.w, acc.w);
                acc.x = fmaf(zq.w, w3.x, acc.x); acc.y = fmaf(zq.w, w3.y, acc.y);
                acc.z = fmaf(zq.w, w3.z, acc.z); acc.w = fmaf(zq.w, w3.w, acc.w);
            }
            sTh[s][j + 0] = tanhf(acc.x);
            sTh[s][j + 1] = tanhf(acc.y);
            sTh[s][j + 2] = tanhf(acc.z);
            sTh[s][j + 3] = tanhf(acc.w);
        }
        __syncthreads();

        // GEMM2 (+residual): sZ[s][i] <- sZ[s][i] + b2[i] + sum_j sTh[s][j]*W2[j][i]
        // In-place is safe: each (s,i) is read/written by exactly one thread,
        // and no other thread reads sZ in this phase.
        if (tid < S * (L / 4)) {
            const int s = tid >> 4;
            const int i = (tid & 15) * 4;
            float4 acc = *(const float4*)&sB2[i];
            #pragma unroll
            for (int j = 0; j < H; j += 4) {
                const float4 tq = *(const float4*)&sTh[s][j];
                const float4 w0 = *(const float4*)&sW2[j + 0][i];
                const float4 w1 = *(const float4*)&sW2[j + 1][i];
                const float4 w2 = *(const float4*)&sW2[j + 2][i];
                const float4 w3 = *(const float4*)&sW2[j + 3][i];
                acc.x = fmaf(tq.x, w0.x, acc.x); acc.y = fmaf(tq.x, w0.y, acc.y);
                acc.z = fmaf(tq.x, w0.z, acc.z); acc.w = fmaf(tq.x, w0.w, acc.w);
                acc.x = fmaf(tq.y, w1.x, acc.x); acc.y = fmaf(tq.y, w1.y, acc.y);
                acc.z = fmaf(tq.y, w1.z, acc.z); acc.w = fmaf(tq.y, w1.w, acc.w);
                acc.x = fmaf(tq.z, w2.x, acc.x); acc.y = fmaf(tq.z, w2.y, acc.y);
                acc.z = fmaf(tq.z, w2.z, acc.z); acc.w = fmaf(tq.z, w2.w, acc.w);
                acc.x = fmaf(tq.w, w3.x, acc.x); acc.y = fmaf(tq.w, w3.y, acc.y);
                acc.z = fmaf(tq.w, w3.z, acc.z); acc.w = fmaf(tq.w, w3.w, acc.w);
            }
            const float4 zold = *(const float4*)&sZ[s][i];
            acc.x += zold.x; acc.y += zold.y; acc.z += zold.z; acc.w += zold.w;
            *(float4*)&sZ[s][i] = acc;   // sZ now holds m_th
        }
        __syncthreads();

        // per-dim moments + Kalman update (threads 0..63, one per l)
        if (tid < L) {
            const int l = tid;
            float sum = 0.0f, sumsq = 0.0f;
            #pragma unroll
            for (int s = 0; s < S; ++s) {
                const float v = sZ[s][l];
                sum   += v;
                sumsq += v * v;
            }
            const float mp  = sum * (1.0f / S);
            const float msq = sumsq * (1.0f / S);
            const float Pp  = sQd[l] + msq - mp * mp;
            const float Jp  = 1.0f / Pp;
            const float Jf  = Jp + Kv;
            const float Pf  = 1.0f / Jf;
            const float mf  = Pf * (Jp * mp + kv);
            const size_t o  = ((size_t)b * T + t) * L + l;
            out_mf[o] = mf;
            out_mp[o] = mp;
            out_Pf[o] = Pf;
            out_Pp[o] = Pp;
            sMf[l]  = mf;
            sSPf[l] = sqrtf(Pf);
        }
        __syncthreads();

        // sample: z_t = m_f + sqrt(P_f) * noise[t]; overwrite sZ, emit z_f
        if (tid < S * (L / 4)) {
            float4 z;
            z.x = sMf[zi + 0] + sSPf[zi + 0] * nv.x;
            z.y = sMf[zi + 1] + sSPf[zi + 1] * nv.y;
            z.z = sMf[zi + 2] + sSPf[zi + 2] * nv.z;
            z.w = sMf[zi + 3] + sSPf[zi + 3] * nv.w;
            *(float4*)&sZ[zs][zi] = z;
            *(float4*)&out_zf[(((size_t)zs * B + b) * T + t) * L + zi] = z;
        }
        __syncthreads();
    }
}

extern "C" void kernel_launch(void* const* d_in, const int* in_sizes, int n_in,
                              void* d_out, int out_size, void* d_ws, size_t ws_size,
                              hipStream_t stream) {
    const float* kk      = (const float*)d_in[0];
    const float* KK      = (const float*)d_in[1];
    const float* noise   = (const float*)d_in[2];
    const float* log_Q   = (const float*)d_in[3];
    const float* m_0     = (const float*)d_in[4];
    const float* log_Q_0 = (const float*)d_in[5];
    const float* W1      = (const float*)d_in[6];
    const float* b1      = (const float*)d_in[7];
    const float* W2      = (const float*)d_in[8];
    const float* b2      = (const float*)d_in[9];
    float* outp          = (float*)d_out;

    nlf_kernel<<<dim3(B), dim3(NT), 0, stream>>>(
        kk, KK, noise, log_Q, m_0, log_Q_0, W1, b1, W2, b2, outp);
}

// Round 2
// 960.489 us; speedup vs baseline: 9.4584x; 9.4584x over previous
//
#include <hip/hip_runtime.h>
#include <math.h>

// NonlinearFilter — Round 2: split-bf16 MFMA for both per-step GEMMs.
// One workgroup per batch element (B=128 independent serial chains).
// Weights live in LDS as transposed hi/lo bf16 pairs; each step:
//   GEMM1 (z@W1) -> tanh -> GEMM2 (th@W2) + residual -> moments -> Kalman -> sample.
// Split-bf16 with all 4 cross terms gives ~17-bit-mantissa products; the
// fp32 round-1 kernel measured absmax 0.031, so error amplification through
// the T=256 recurrence is ~1e4; 1e-5-level per-step error keeps us <0.65.

namespace {
constexpr int B = 128;
constexpr int T = 256;
constexpr int L = 64;
constexpr int S = 25;
constexpr int H = 128;
constexpr int NT = 512;          // 8 waves
constexpr int LP = 72;           // padded L row (bf16): 144 B stride, 16B-aligned
constexpr int HP = 144;          // padded H row (bf16): 288 B stride
constexpr int LPF = 72;          // padded L row (fp32) for sZf

typedef __bf16 bf16x8 __attribute__((ext_vector_type(8)));
typedef float floatx4 __attribute__((ext_vector_type(4)));

__device__ __forceinline__ float softplus_f(float x) {
    return fmaxf(x, 0.0f) + log1pf(expf(-fabsf(x)));
}
} // namespace

__global__ __launch_bounds__(NT, 1)
void nlf_kernel(const float* __restrict__ kk,
                const float* __restrict__ KK,
                const float* __restrict__ noise,
                const float* __restrict__ log_Q,
                const float* __restrict__ m_0,
                const float* __restrict__ log_Q_0,
                const float* __restrict__ W1,
                const float* __restrict__ b1,
                const float* __restrict__ W2,
                const float* __restrict__ b2,
                float* __restrict__ out)
{
    const int b    = blockIdx.x;
    const int tid  = threadIdx.x;
    const int w    = tid >> 6;
    const int lane = tid & 63;
    const int row16 = lane & 15;
    const int quad  = lane >> 4;

    // weights, transposed, split hi/lo
    __shared__ __align__(16) __bf16 sW1h[H][LP];   // W1^T: [j][l]
    __shared__ __align__(16) __bf16 sW1l[H][LP];
    __shared__ __align__(16) __bf16 sW2h[L][HP];   // W2^T: [i][j]
    __shared__ __align__(16) __bf16 sW2l[L][HP];
    // state
    __shared__ __align__(16) __bf16 sZh[32][LP];   // z (bf16 hi/lo), rows 25..31 zero
    __shared__ __align__(16) __bf16 sZl[32][LP];
    __shared__ __align__(16) __bf16 sThh[32][HP];  // tanh activations hi/lo
    __shared__ __align__(16) __bf16 sThl[32][HP];
    __shared__ __align__(16) float  sZf[32][LPF];  // fp32 z for exact residual
    __shared__ float sB1f[H], sB2f[L], sQd[L], sMf[L], sSPf[L];
    __shared__ float sSum[2][L], sSsq[2][L];

    // ---- stage weights / constants (once) ----
    for (int i = tid; i < L * H; i += NT) {      // W1 (L=64 rows, H=128 cols)
        const int l = i >> 7, j = i & 127;
        const float v = W1[i];
        const __bf16 hi = (__bf16)v;
        sW1h[j][l] = hi;
        sW1l[j][l] = (__bf16)(v - (float)hi);
    }
    for (int i = tid; i < H * L; i += NT) {      // W2 (H=128 rows, L=64 cols)
        const int j = i >> 6, l2 = i & 63;
        const float v = W2[i];
        const __bf16 hi = (__bf16)v;
        sW2h[l2][j] = hi;
        sW2l[l2][j] = (__bf16)(v - (float)hi);
    }
    if (tid < H) sB1f[tid] = b1[tid];
    if (tid < L) {
        sB2f[tid] = b2[tid];
        sQd[tid]  = softplus_f(log_Q[tid]);
    }
    // zero padding rows 25..31 of z (never rewritten; keeps GEMM1 pad rows finite)
    for (int i = tid; i < 7 * LP; i += NT) {
        sZh[25 + i / LP][i % LP] = (__bf16)0.0f;
        sZl[25 + i / LP][i % LP] = (__bf16)0.0f;
    }

    float* out_zf = out;                                  // (S,B,T,L)
    float* out_mf = out + (size_t)S * B * T * L;          // (B,T,L)
    float* out_mp = out_mf + (size_t)B * T * L;
    float* out_Pf = out_mp + (size_t)B * T * L;
    float* out_Pp = out_Pf + (size_t)B * T * L;

    // ---- t = 0 ----
    if (tid < L) {
        const int l = tid;
        const float P0 = softplus_f(log_Q_0[l]);
        const float J0 = 1.0f / P0;
        const float h0 = J0 * m_0[l];
        const float Kv = KK[((size_t)b * T + 0) * L + l];
        const float kv = kk[((size_t)b * T + 0) * L + l];
        const float Jf = J0 + Kv;
        const float Pf = 1.0f / Jf;
        const float mf = Pf * (h0 + kv);
        const size_t o = ((size_t)b * T + 0) * L + l;
        out_mf[o] = mf;
        out_mp[o] = m_0[l];
        out_Pf[o] = Pf;
        out_Pp[o] = P0;
        sMf[l]  = mf;
        sSPf[l] = sqrtf(Pf);
    }
    __syncthreads();

    if (tid < S * (L / 4)) {
        const int s = tid >> 4;
        const int i = (tid & 15) * 4;
        const float4 nv = *(const float4*)&noise[(((size_t)0 * S + s) * B + b) * L + i];
        float4 z;
        z.x = sMf[i + 0] + sSPf[i + 0] * nv.x;
        z.y = sMf[i + 1] + sSPf[i + 1] * nv.y;
        z.z = sMf[i + 2] + sSPf[i + 2] * nv.z;
        z.w = sMf[i + 3] + sSPf[i + 3] * nv.w;
        *(float4*)&sZf[s][i] = z;
        #pragma unroll
        for (int c = 0; c < 4; ++c) {
            const float zv = (&z.x)[c];
            const __bf16 hi = (__bf16)zv;
            sZh[s][i + c] = hi;
            sZl[s][i + c] = (__bf16)(zv - (float)hi);
        }
        *(float4*)&out_zf[(((size_t)s * B + b) * T + 0) * L + i] = z;
    }
    __syncthreads();

    // ---- main scan ----
    for (int t = 1; t < T; ++t) {
        // prefetch per-step inputs
        float kv = 0.0f, Kv = 0.0f;
        if (tid < L) {
            kv = kk[((size_t)b * T + t) * L + tid];
            Kv = KK[((size_t)b * T + t) * L + tid];
        }
        float4 nv = make_float4(0.f, 0.f, 0.f, 0.f);
        int zs = 0, zi = 0;
        if (tid < S * (L / 4)) {
            zs = tid >> 4;
            zi = (tid & 15) * 4;
            nv = *(const float4*)&noise[(((size_t)t * S + zs) * B + b) * L + zi];
        }

        // ===== GEMM1: C1[s][j] = z @ W1, K=64; wave w -> mt=w&1, nt in {2*(w>>1), +1}
        {
            const int mt = w & 1;
            const int nt0 = (w >> 1) * 2;
            const bf16x8 a0h = *(const bf16x8*)&sZh[mt * 16 + row16][ 0 + quad * 8];
            const bf16x8 a0l = *(const bf16x8*)&sZl[mt * 16 + row16][ 0 + quad * 8];
            const bf16x8 a1h = *(const bf16x8*)&sZh[mt * 16 + row16][32 + quad * 8];
            const bf16x8 a1l = *(const bf16x8*)&sZl[mt * 16 + row16][32 + quad * 8];
            #pragma unroll
            for (int tt = 0; tt < 2; ++tt) {
                const int nt = nt0 + tt;
                const bf16x8 b0h = *(const bf16x8*)&sW1h[nt * 16 + row16][ 0 + quad * 8];
                const bf16x8 b0l = *(const bf16x8*)&sW1l[nt * 16 + row16][ 0 + quad * 8];
                const bf16x8 b1h = *(const bf16x8*)&sW1h[nt * 16 + row16][32 + quad * 8];
                const bf16x8 b1l = *(const bf16x8*)&sW1l[nt * 16 + row16][32 + quad * 8];
                floatx4 c = {0.f, 0.f, 0.f, 0.f};
                c = __builtin_amdgcn_mfma_f32_16x16x32_bf16(a0h, b0h, c, 0, 0, 0);
                c = __builtin_amdgcn_mfma_f32_16x16x32_bf16(a0l, b0h, c, 0, 0, 0);
                c = __builtin_amdgcn_mfma_f32_16x16x32_bf16(a0h, b0l, c, 0, 0, 0);
                c = __builtin_amdgcn_mfma_f32_16x16x32_bf16(a0l, b0l, c, 0, 0, 0);
                c = __builtin_amdgcn_mfma_f32_16x16x32_bf16(a1h, b1h, c, 0, 0, 0);
                c = __builtin_amdgcn_mfma_f32_16x16x32_bf16(a1l, b1h, c, 0, 0, 0);
                c = __builtin_amdgcn_mfma_f32_16x16x32_bf16(a1h, b1l, c, 0, 0, 0);
                c = __builtin_amdgcn_mfma_f32_16x16x32_bf16(a1l, b1l, c, 0, 0, 0);
                // epilogue: +b1, tanh, split to bf16 hi/lo into sTh
                const int ncol = nt * 16 + row16;
                const float bias = sB1f[ncol];
                #pragma unroll
                for (int r = 0; r < 4; ++r) {
                    const int m = mt * 16 + quad * 4 + r;
                    const float th = tanhf(c[r] + bias);
                    const __bf16 hi = (__bf16)th;
                    sThh[m][ncol] = hi;
                    sThl[m][ncol] = (__bf16)(th - (float)hi);
                }
            }
        }
        __syncthreads();

        // ===== GEMM2: C2[s][i] = th @ W2, K=128; wave w -> mt=w&1, nt=w>>1
        {
            const int mt = w & 1;
            const int nt = w >> 1;
            floatx4 c = {0.f, 0.f, 0.f, 0.f};
            #pragma unroll
            for (int ks = 0; ks < 4; ++ks) {
                const int k0 = ks * 32;
                const bf16x8 ah = *(const bf16x8*)&sThh[mt * 16 + row16][k0 + quad * 8];
                const bf16x8 al = *(const bf16x8*)&sThl[mt * 16 + row16][k0 + quad * 8];
                const bf16x8 bh = *(const bf16x8*)&sW2h[nt * 16 + row16][k0 + quad * 8];
                const bf16x8 bl = *(const bf16x8*)&sW2l[nt * 16 + row16][k0 + quad * 8];
                c = __builtin_amdgcn_mfma_f32_16x16x32_bf16(ah, bh, c, 0, 0, 0);
                c = __builtin_amdgcn_mfma_f32_16x16x32_bf16(al, bh, c, 0, 0, 0);
                c = __builtin_amdgcn_mfma_f32_16x16x32_bf16(ah, bl, c, 0, 0, 0);
                c = __builtin_amdgcn_mfma_f32_16x16x32_bf16(al, bl, c, 0, 0, 0);
            }
            // epilogue: m_th = C2 + b2 + z (fp32); masked moment partials
            const int ncol = nt * 16 + row16;      // l index
            const float b2v = sB2f[ncol];
            float sum = 0.0f, ssq = 0.0f;
            #pragma unroll
            for (int r = 0; r < 4; ++r) {
                const int m = mt * 16 + quad * 4 + r;   // s index
                const float v = c[r] + b2v + sZf[m][ncol];
                if (m < S) { sum += v; ssq += v * v; }
            }
            sum += __shfl_xor(sum, 16); ssq += __shfl_xor(ssq, 16);
            sum += __shfl_xor(sum, 32); ssq += __shfl_xor(ssq, 32);
            if (quad == 0) {
                sSum[mt][ncol] = sum;
                sSsq[mt][ncol] = ssq;
            }
        }
        __syncthreads();

        // ===== moments + Kalman (one thread per l)
        if (tid < L) {
            const int l = tid;
            const float sum = sSum[0][l] + sSum[1][l];
            const float ssq = sSsq[0][l] + sSsq[1][l];
            const float mp  = sum * (1.0f / S);
            const float msq = ssq * (1.0f / S);
            const float Pp  = sQd[l] + msq - mp * mp;
            const float Jp  = 1.0f / Pp;
            const float Jf  = Jp + Kv;
            const float Pf  = 1.0f / Jf;
            const float mf  = Pf * (Jp * mp + kv);
            const size_t o  = ((size_t)b * T + t) * L + l;
            out_mf[o] = mf;
            out_mp[o] = mp;
            out_Pf[o] = Pf;
            out_Pp[o] = Pp;
            sMf[l]  = mf;
            sSPf[l] = sqrtf(Pf);
        }
        __syncthreads();

        // ===== sample z_t
        if (tid < S * (L / 4)) {
            float4 z;
            z.x = sMf[zi + 0] + sSPf[zi + 0] * nv.x;
            z.y = sMf[zi + 1] + sSPf[zi + 1] * nv.y;
            z.z = sMf[zi + 2] + sSPf[zi + 2] * nv.z;
            z.w = sMf[zi + 3] + sSPf[zi + 3] * nv.w;
            *(float4*)&sZf[zs][zi] = z;
            #pragma unroll
            for (int c = 0; c < 4; ++c) {
                const float zv = (&z.x)[c];
                const __bf16 hi = (__bf16)zv;
                sZh[zs][zi + c] = hi;
                sZl[zs][zi + c] = (__bf16)(zv - (float)hi);
            }
            *(float4*)&out_zf[(((size_t)zs * B + b) * T + t) * L + zi] = z;
        }
        __syncthreads();
    }
}

extern "C" void kernel_launch(void* const* d_in, const int* in_sizes, int n_in,
                              void* d_out, int out_size, void* d_ws, size_t ws_size,
                              hipStream_t stream) {
    const float* kk      = (const float*)d_in[0];
    const float* KK      = (const float*)d_in[1];
    const float* noise   = (const float*)d_in[2];
    const float* log_Q   = (const float*)d_in[3];
    const float* m_0     = (const float*)d_in[4];
    const float* log_Q_0 = (const float*)d_in[5];
    const float* W1      = (const float*)d_in[6];
    const float* b1      = (const float*)d_in[7];
    const float* W2      = (const float*)d_in[8];
    const float* b2      = (const float*)d_in[9];
    float* outp          = (float*)d_out;

    nlf_kernel<<<dim3(B), dim3(NT), 0, stream>>>(
        kk, KK, noise, log_Q, m_0, log_Q_0, W1, b1, W2, b2, outp);
}